// Round 2
// baseline (316.057 us; speedup 1.0000x reference)
//
#include <hip/hip_runtime.h>

// Problem constants (fixed by the reference)
#define B_   2
#define DZ   41
#define HY   400
#define WX   352
#define NVOX 40000
#define PD   43      // DZ+2
#define PH   402     // HY+2
#define PW   354     // WX+2
#define DO_  21
#define HO_  200
#define WO_  176
#define C1   128
#define GRID_CELLS (B_*PD*PH*PW)        // 12,238,488
#define OUT_POS    (B_*DO_*HO_*WO_)     // 1,478,400
#define OUT_BYTES  ((size_t)OUT_POS * 32 * sizeof(float))   // 189,235,200 B

// Journal:
// R4: 306.5 us. R5 (exact-size out memset): 306.0 us -> NO CHANGE. The 739,200 KB
//     fillBufferAligned dispatches are the HARNESS reset, not ours; untimed. The
//     306 us is all our kernels; k_subm1 ~180 us dominates (R3 note).
// R6: voxel grid occupancy is 0.35% -> avg 1.09 valid taps of 27. k_subm1 was
//     latency-bound on a single 128-FMA dependent chain and iterated all 27 taps.
//     Now: k_nbr compacts valid taps into packed (k<<16|idx) + cnt per voxel;
//     subm1/subm2 loop only over valid taps, 4 accumulator chains, float4 loads.
//     Predicted total 306 -> ~150 us.

// ---- build padded dense grid of (voxel id + 1), 0 = empty ----
__global__ void k_build(const int* __restrict__ coors, unsigned short* __restrict__ grid) {
    int n = blockIdx.x * blockDim.x + threadIdx.x;
    if (n >= NVOX) return;
    int b = coors[4*n+0], z = coors[4*n+1], y = coors[4*n+2], x = coors[4*n+3];
    grid[((b*PD + z+1)*PH + y+1)*PW + x+1] = (unsigned short)(n + 1);
}

// ---- per-voxel compacted neighbor list: list[n][t] = (k<<16)|idx, cnt[n] ----
// idx < 40000 fits in 16 bits; k in 0..26.
__global__ void k_nbr(const int* __restrict__ coors, const unsigned short* __restrict__ grid,
                      int* __restrict__ list, int* __restrict__ cnt) {
    int n = blockIdx.x * blockDim.x + threadIdx.x;
    if (n >= NVOX) return;
    int b = coors[4*n+0], z = coors[4*n+1], y = coors[4*n+2], x = coors[4*n+3];
    int c = 0;
    int* lp = list + n * 27;
    #pragma unroll
    for (int dz = 0; dz < 3; ++dz) {
        #pragma unroll
        for (int dy = 0; dy < 3; ++dy) {
            const unsigned short* row = grid + ((size_t)(b*PD + z + dz)*PH + (y + dy))*PW + x;
            #pragma unroll
            for (int dx = 0; dx < 3; ++dx) {
                int id = (int)row[dx] - 1;
                if (id >= 0) lp[c++] = ((dz*9 + dy*3 + dx) << 16) | id;
            }
        }
    }
    cnt[n] = c;
}

// ---- subm conv 1: 128 -> 16, ReLU. Only valid taps; 4 acc chains; float4 feat ----
__global__ void k_subm1(const float* __restrict__ feat,
                        const float* __restrict__ W1,
                        const int* __restrict__ list, const int* __restrict__ cnt,
                        float* __restrict__ x1) {
    __shared__ int s_list[16][28];
    __shared__ int s_cnt[16];
    int base = blockIdx.x * 16;
    if (threadIdx.x < 16) {
        int n = base + threadIdx.x;
        s_cnt[threadIdx.x] = (n < NVOX) ? cnt[n] : 0;
    }
    for (int i = threadIdx.x; i < 16*27; i += 256) {
        int v = i / 27, k = i % 27;
        int n = base + v;
        s_list[v][k] = (n < NVOX) ? list[n*27 + k] : 0;
    }
    __syncthreads();
    int v = threadIdx.x >> 4, d = threadIdx.x & 15;
    int n = base + v;
    if (n >= NVOX) return;
    int m = s_cnt[v];
    float a0 = 0.f, a1 = 0.f, a2 = 0.f, a3 = 0.f;
    for (int t = 0; t < m; ++t) {
        int e = s_list[v][t];
        int k = e >> 16, idx = e & 0xFFFF;
        const float4* f4 = (const float4*)(feat + (size_t)idx * C1);
        const float* w = W1 + k * (C1*16) + d;
        #pragma unroll
        for (int c4 = 0; c4 < 32; ++c4) {
            float4 fv = f4[c4];
            const float* wp = w + c4 * 64;   // 4 consecutive c's, stride 16 floats
            a0 += fv.x * wp[0];
            a1 += fv.y * wp[16];
            a2 += fv.z * wp[32];
            a3 += fv.w * wp[48];
        }
    }
    x1[n*16 + d] = fmaxf((a0 + a1) + (a2 + a3), 0.f);
}

// ---- subm conv 2: 16 -> 16, ReLU. W2 in LDS; only valid taps ----
__global__ void k_subm2(const float* __restrict__ x1,
                        const float* __restrict__ W2,
                        const int* __restrict__ list, const int* __restrict__ cnt,
                        float* __restrict__ x2) {
    __shared__ int   s_list[16][28];
    __shared__ int   s_cnt[16];
    __shared__ float s_w2[27*16*16];
    for (int i = threadIdx.x; i < 27*16*16; i += 256) s_w2[i] = W2[i];
    int base = blockIdx.x * 16;
    if (threadIdx.x < 16) {
        int n = base + threadIdx.x;
        s_cnt[threadIdx.x] = (n < NVOX) ? cnt[n] : 0;
    }
    for (int i = threadIdx.x; i < 16*27; i += 256) {
        int v = i / 27, k = i % 27;
        int n = base + v;
        s_list[v][k] = (n < NVOX) ? list[n*27 + k] : 0;
    }
    __syncthreads();
    int v = threadIdx.x >> 4, d = threadIdx.x & 15;
    int n = base + v;
    if (n >= NVOX) return;
    int m = s_cnt[v];
    float a0 = 0.f, a1 = 0.f, a2 = 0.f, a3 = 0.f;
    for (int t = 0; t < m; ++t) {
        int e = s_list[v][t];
        int k = e >> 16, idx = e & 0xFFFF;
        const float4* x4 = (const float4*)(x1 + (size_t)idx * 16);
        float4 xa = x4[0], xb = x4[1], xc = x4[2], xd = x4[3];
        const float* wp = s_w2 + k * 256 + d;
        a0 += xa.x * wp[0*16]  + xa.y * wp[1*16]  + xa.z * wp[2*16]  + xa.w * wp[3*16];
        a1 += xb.x * wp[4*16]  + xb.y * wp[5*16]  + xb.z * wp[6*16]  + xb.w * wp[7*16];
        a2 += xc.x * wp[8*16]  + xc.y * wp[9*16]  + xc.z * wp[10*16] + xc.w * wp[11*16];
        a3 += xd.x * wp[12*16] + xd.y * wp[13*16] + xd.z * wp[14*16] + xd.w * wp[15*16];
    }
    x2[n*16 + d] = fmaxf((a0 + a1) + (a2 + a3), 0.f);
}

// ---- valid downsample taps for one axis, from PADDED input coord ----
__device__ __forceinline__ int axis_taps(int pcoord, int outdim, int* ds, int* ps) {
    if (pcoord & 1) { ds[0] = 1; ps[0] = pcoord >> 1; return 1; }
    int h = pcoord >> 1, nu = 0;
    if (h < outdim) { ds[nu] = 0; ps[nu] = h; nu++; }
    ds[nu] = 2; ps[nu] = h - 1; nu++;
    return nu;
}

// ---- stride-2 conv 16 -> 32 as scatter: block = 8 voxels x 32 channels ----
__global__ void k_scatter(const float* __restrict__ x2,
                          const float* __restrict__ W3,
                          const int* __restrict__ coors,
                          float* __restrict__ out) {
    int v = threadIdx.x >> 5, d = threadIdx.x & 31;
    int n = blockIdx.x * 8 + v;
    if (n >= NVOX) return;
    int b  = coors[4*n+0];
    int zp = coors[4*n+1] + 1, yp = coors[4*n+2] + 1, xp = coors[4*n+3] + 1;
    int dz[2], pz[2], dy[2], py[2], dx[2], px[2];
    int nz = axis_taps(zp, DO_, dz, pz);
    int ny = axis_taps(yp, HO_, dy, py);
    int nx = axis_taps(xp, WO_, dx, px);
    const float4* xr = (const float4*)(x2 + (size_t)n * 16);
    float r[16];
    *(float4*)(r + 0)  = xr[0];
    *(float4*)(r + 4)  = xr[1];
    *(float4*)(r + 8)  = xr[2];
    *(float4*)(r + 12) = xr[3];
    int bofs = b * (DO_*HO_*WO_);
    for (int iz = 0; iz < nz; ++iz)
        for (int iy = 0; iy < ny; ++iy)
            for (int ix = 0; ix < nx; ++ix) {
                int k = dz[iz]*9 + dy[iy]*3 + dx[ix];
                int p = bofs + (pz[iz]*HO_ + py[iy])*WO_ + px[ix];
                const float* w = W3 + k*512 + d;   // W3[k][c][d], stride 32 over c
                float acc = 0.f;
                #pragma unroll
                for (int c = 0; c < 16; ++c) acc += r[c] * w[c * 32];
                atomicAdd(out + (size_t)p * 32 + d, acc);
            }
}

// ---- idempotent ReLU over touched positions ----
__global__ void k_relu(const int* __restrict__ coors, float* __restrict__ out) {
    int v = threadIdx.x >> 5, d = threadIdx.x & 31;
    int n = blockIdx.x * 8 + v;
    if (n >= NVOX) return;
    int b  = coors[4*n+0];
    int zp = coors[4*n+1] + 1, yp = coors[4*n+2] + 1, xp = coors[4*n+3] + 1;
    int dz[2], pz[2], dy[2], py[2], dx[2], px[2];
    int nz = axis_taps(zp, DO_, dz, pz);
    int ny = axis_taps(yp, HO_, dy, py);
    int nx = axis_taps(xp, WO_, dx, px);
    int bofs = b * (DO_*HO_*WO_);
    for (int iz = 0; iz < nz; ++iz)
        for (int iy = 0; iy < ny; ++iy)
            for (int ix = 0; ix < nx; ++ix) {
                int p = bofs + (pz[iz]*HO_ + py[iy])*WO_ + px[ix];
                size_t o = (size_t)p * 32 + d;
                out[o] = fmaxf(out[o], 0.f);
            }
}

extern "C" void kernel_launch(void* const* d_in, const int* in_sizes, int n_in,
                              void* d_out, int out_size, void* d_ws, size_t ws_size,
                              hipStream_t stream) {
    const float* feat  = (const float*)d_in[0];  // f32 (N,128)
    const int*   coors = (const int*)d_in[1];    // int32 (N,4)
    const float* W1    = (const float*)d_in[2];  // f32 (27,128,16)
    const float* W2    = (const float*)d_in[3];  // f32 (27,16,16)
    const float* W3    = (const float*)d_in[4];  // f32 (27,16,32)
    float* out = (float*)d_out;                  // f32 (2,21,200,176,32)

    char* ws = (char*)d_ws;
    size_t off = 0;
    unsigned short* grid = (unsigned short*)(ws + off);
    off += (((size_t)GRID_CELLS*2) + 255) & ~(size_t)255;
    int* list = (int*)(ws + off); off += (((size_t)NVOX*27*4) + 255) & ~(size_t)255;
    int* cnt  = (int*)(ws + off); off += (((size_t)NVOX*4)    + 255) & ~(size_t)255;
    float* x1 = (float*)(ws + off); off += (((size_t)NVOX*16*4) + 255) & ~(size_t)255;
    float* x2 = (float*)(ws + off);

    hipMemsetAsync(grid, 0x00, (size_t)GRID_CELLS * 2, stream);     // grid = 0 (empty)
    hipMemsetAsync(out, 0x00, OUT_BYTES, stream);
    k_build<<<(NVOX + 255) / 256, 256, 0, stream>>>(coors, grid);
    k_nbr<<<(NVOX + 255) / 256, 256, 0, stream>>>(coors, grid, list, cnt);
    k_subm1<<<(NVOX + 15) / 16, 256, 0, stream>>>(feat, W1, list, cnt, x1);
    k_subm2<<<(NVOX + 15) / 16, 256, 0, stream>>>(x1, W2, list, cnt, x2);
    k_scatter<<<(NVOX + 7) / 8, 256, 0, stream>>>(x2, W3, coors, out);
    k_relu<<<(NVOX + 7) / 8, 256, 0, stream>>>(coors, out);
}